// Round 8
// baseline (2441.951 us; speedup 1.0000x reference)
//
#include <hip/hip_runtime.h>
#include <stdint.h>

#define NN 6000
#define EE 120000
#define DD 128
#define CC 384
#define HDIM 512
#define OUT_NODES (NN*DD)
#define OUT_TOTAL (NN*DD + EE*DD)

typedef unsigned short u16;
typedef __bf16 bf16x8 __attribute__((ext_vector_type(8)));
typedef float f32x4 __attribute__((ext_vector_type(4)));

__device__ __forceinline__ float bf2f(u16 u){ union{unsigned i; float f;} x; x.i=(unsigned)u<<16; return x.f; }
__device__ __forceinline__ u16 f2bf(float f){ union{unsigned i; float f;} x; x.f=f; unsigned r=(x.i + 0x7fffu + ((x.i>>16)&1u))>>16; return (u16)r; }
__device__ __forceinline__ float gelu_f(float v){ return 0.5f*v*(1.f + erff(v*0.70710678118654752f)); }

union V8 { u16 s[8]; uint4 v; };

// epi: 2 = lrelu->fp32 ; 3 = bias->fp32 ; 4 = gelu->fp32
__device__ __forceinline__ void gemm_epilogue(
    f32x4 acc[4][4], const float* bias, float* Cp, int M, int ldc, int epi,
    int m0, int n0, int lane, int wm, int wn)
{
  const int rl = wm*64 + (lane >> 4) * 4;
  const int cl = wn*64 + (lane & 15);
#pragma unroll
  for (int ni = 0; ni < 4; ++ni) {
    int gn = n0 + cl + ni*16;
    float bvv = bias ? bias[gn] : 0.f;
#pragma unroll
    for (int mi = 0; mi < 4; ++mi) {
#pragma unroll
      for (int rg = 0; rg < 4; ++rg) {
        int gm = m0 + rl + mi*16 + rg;
        if (gm < M) {
          float v = acc[mi][ni][rg] + bvv;
          if (epi == 4)      v = gelu_f(v);
          else if (epi == 2) v = (v > 0.f) ? v : 0.2f*v;
          Cp[(size_t)gm*ldc + gn] = v;
        }
      }
    }
  }
}

// ---------- GEMM, split-A x split-B (3 MFMAs/tile: AhBh + AhBl + AlBh): ~fp32 fidelity ----------
__global__ __launch_bounds__(256) void k_gemm_sp3(
    const float* __restrict__ A, const u16* __restrict__ Bth, const u16* __restrict__ Btl,
    const float* __restrict__ bias, float* __restrict__ Cp, int M, int K, int ldc, int epi)
{
  __shared__ __align__(16) u16 Ah[128*32];
  __shared__ __align__(16) u16 Al[128*32];
  __shared__ __align__(16) u16 Bh[128*32];
  __shared__ __align__(16) u16 Bl[128*32];
  const int tid = threadIdx.x, lane = tid & 63;
  const int m0 = blockIdx.x * 128, n0 = blockIdx.y * 128;
  const int wm = (tid >> 6) & 1, wn = (tid >> 7) & 1;
  f32x4 acc[4][4] = {};
  for (int kt = 0; kt < K; kt += 32) {
    float4 f0[2], f1[2]; uint4 bh[2], bl[2];
#pragma unroll
    for (int r = 0; r < 2; ++r) {
      int c = r*256 + tid, m = c >> 2, q = c & 3;
      int gm = m0 + m; if (gm > M-1) gm = M-1;
      const float* pa = A + (size_t)gm * K + kt + q*8;
      f0[r] = *(const float4*)pa; f1[r] = *(const float4*)(pa + 4);
      size_t bo = (size_t)(n0 + m) * K + kt + q*8;
      bh[r] = *(const uint4*)(Bth + bo);
      bl[r] = *(const uint4*)(Btl + bo);
    }
    __syncthreads();
#pragma unroll
    for (int r = 0; r < 2; ++r) {
      int c = r*256 + tid, m = c >> 2, q = c & 3;
      float xs[8] = { f0[r].x,f0[r].y,f0[r].z,f0[r].w, f1[r].x,f1[r].y,f1[r].z,f1[r].w };
      V8 hi, lo;
#pragma unroll
      for (int j = 0; j < 8; ++j) {
        u16 h = f2bf(xs[j]); hi.s[j] = h; lo.s[j] = f2bf(xs[j] - bf2f(h));
      }
      *(uint4*)(Ah + m*32 + q*8) = hi.v;
      *(uint4*)(Al + m*32 + q*8) = lo.v;
      *(uint4*)(Bh + m*32 + q*8) = bh[r];
      *(uint4*)(Bl + m*32 + q*8) = bl[r];
    }
    __syncthreads();
    const int qq = lane >> 4, ml = lane & 15;
    bf16x8 ah[4], al[4], vh[4], vl[4];
#pragma unroll
    for (int mi = 0; mi < 4; ++mi) {
      ah[mi] = *(const bf16x8*)(Ah + (wm*64 + mi*16 + ml)*32 + qq*8);
      al[mi] = *(const bf16x8*)(Al + (wm*64 + mi*16 + ml)*32 + qq*8);
    }
#pragma unroll
    for (int ni = 0; ni < 4; ++ni) {
      vh[ni] = *(const bf16x8*)(Bh + (wn*64 + ni*16 + ml)*32 + qq*8);
      vl[ni] = *(const bf16x8*)(Bl + (wn*64 + ni*16 + ml)*32 + qq*8);
    }
#pragma unroll
    for (int mi = 0; mi < 4; ++mi)
#pragma unroll
      for (int ni = 0; ni < 4; ++ni) {
        acc[mi][ni] = __builtin_amdgcn_mfma_f32_16x16x32_bf16(ah[mi], vl[ni], acc[mi][ni], 0, 0, 0);
        acc[mi][ni] = __builtin_amdgcn_mfma_f32_16x16x32_bf16(al[mi], vh[ni], acc[mi][ni], 0, 0, 0);
        acc[mi][ni] = __builtin_amdgcn_mfma_f32_16x16x32_bf16(ah[mi], vh[ni], acc[mi][ni], 0, 0, 0);
      }
  }
  gemm_epilogue(acc, bias, Cp, M, ldc, epi, m0, n0, lane, wm, wn);
}

// ---------- GEMM, gathered split-A x split-B: row ge = [nodes_f[src]|nodes_f[snk]|eattr_f[ge]], K=384 ----
__global__ __launch_bounds__(256) void k_gemm_gsp3(
    const float* __restrict__ nodes_f, const float* __restrict__ eattr_f,
    const int* __restrict__ src, const int* __restrict__ snk, int rowoff,
    const u16* __restrict__ Bth, const u16* __restrict__ Btl,
    const float* __restrict__ bias, float* __restrict__ Cp, int M, int ldc, int epi)
{
  __shared__ __align__(16) u16 Ah[128*32];
  __shared__ __align__(16) u16 Al[128*32];
  __shared__ __align__(16) u16 Bh[128*32];
  __shared__ __align__(16) u16 Bl[128*32];
  const int tid = threadIdx.x, lane = tid & 63;
  const int m0 = blockIdx.x * 128, n0 = blockIdx.y * 128;
  const int wm = (tid >> 6) & 1, wn = (tid >> 7) & 1;
  const float* p0[2]; const float* p1[2]; const float* p2[2];
#pragma unroll
  for (int r = 0; r < 2; ++r) {
    int c = r*256 + tid, m = c >> 2;
    int gl = m0 + m; if (gl > M-1) gl = M-1;
    int ge = rowoff + gl;
    p0[r] = nodes_f + (size_t)src[ge]*DD;
    p1[r] = nodes_f + (size_t)snk[ge]*DD;
    p2[r] = eattr_f + (size_t)ge*DD;
  }
  f32x4 acc[4][4] = {};
  for (int kt = 0; kt < CC; kt += 32) {
    float4 f0[2], f1[2]; uint4 bh[2], bl[2];
#pragma unroll
    for (int r = 0; r < 2; ++r) {
      int c = r*256 + tid, m = c >> 2, q = c & 3;
      int col = kt + q*8;
      const float* pf = (col < 128) ? (p0[r] + col) : (col < 256) ? (p1[r] + col - 128) : (p2[r] + col - 256);
      f0[r] = *(const float4*)pf; f1[r] = *(const float4*)(pf + 4);
      size_t bo = (size_t)(n0 + m) * CC + kt + q*8;
      bh[r] = *(const uint4*)(Bth + bo);
      bl[r] = *(const uint4*)(Btl + bo);
    }
    __syncthreads();
#pragma unroll
    for (int r = 0; r < 2; ++r) {
      int c = r*256 + tid, m = c >> 2, q = c & 3;
      float xs[8] = { f0[r].x,f0[r].y,f0[r].z,f0[r].w, f1[r].x,f1[r].y,f1[r].z,f1[r].w };
      V8 hi, lo;
#pragma unroll
      for (int j = 0; j < 8; ++j) {
        u16 h = f2bf(xs[j]); hi.s[j] = h; lo.s[j] = f2bf(xs[j] - bf2f(h));
      }
      *(uint4*)(Ah + m*32 + q*8) = hi.v;
      *(uint4*)(Al + m*32 + q*8) = lo.v;
      *(uint4*)(Bh + m*32 + q*8) = bh[r];
      *(uint4*)(Bl + m*32 + q*8) = bl[r];
    }
    __syncthreads();
    const int qq = lane >> 4, ml = lane & 15;
    bf16x8 ah[4], al[4], vh[4], vl[4];
#pragma unroll
    for (int mi = 0; mi < 4; ++mi) {
      ah[mi] = *(const bf16x8*)(Ah + (wm*64 + mi*16 + ml)*32 + qq*8);
      al[mi] = *(const bf16x8*)(Al + (wm*64 + mi*16 + ml)*32 + qq*8);
    }
#pragma unroll
    for (int ni = 0; ni < 4; ++ni) {
      vh[ni] = *(const bf16x8*)(Bh + (wn*64 + ni*16 + ml)*32 + qq*8);
      vl[ni] = *(const bf16x8*)(Bl + (wn*64 + ni*16 + ml)*32 + qq*8);
    }
#pragma unroll
    for (int mi = 0; mi < 4; ++mi)
#pragma unroll
      for (int ni = 0; ni < 4; ++ni) {
        acc[mi][ni] = __builtin_amdgcn_mfma_f32_16x16x32_bf16(ah[mi], vl[ni], acc[mi][ni], 0, 0, 0);
        acc[mi][ni] = __builtin_amdgcn_mfma_f32_16x16x32_bf16(al[mi], vh[ni], acc[mi][ni], 0, 0, 0);
        acc[mi][ni] = __builtin_amdgcn_mfma_f32_16x16x32_bf16(ah[mi], vh[ni], acc[mi][ni], 0, 0, 0);
      }
  }
  gemm_epilogue(acc, bias, Cp, M, ldc, epi, m0, n0, lane, wm, wn);
}

// ---------------- small kernels ----------------
__global__ void k_detect(const u16* __restrict__ d, int n, int* __restrict__ flag) {
  __shared__ int cnt;
  if (threadIdx.x == 0) cnt = 0;
  __syncthreads();
  int c = 0;
  for (int i = threadIdx.x; i < n; i += blockDim.x) {
    int e = (d[i] >> 7) & 0xff;
    if (e >= 0xC0) ++c;
  }
  atomicAdd(&cnt, c);
  __syncthreads();
  if (threadIdx.x == 0) *flag = (cnt > 16) ? 1 : 0;
}

// canonicalize all float inputs to FP32 arena (upconvert bf16 losslessly, or copy fp32)
struct ConvDesc { const void* src; float* dst; int n; };
struct ConvArgs { ConvDesc d[30]; };
__global__ void k_conv32(ConvArgs a, const int* __restrict__ flag) {
  ConvDesc de = a.d[blockIdx.y];
  int fp = *flag;
  for (int i = blockIdx.x*256 + threadIdx.x; i < de.n; i += gridDim.x*256)
    de.dst[i] = fp ? ((const float*)de.src)[i] : bf2f(((const u16*)de.src)[i]);
}

// pack weights from fp32 arena to [N,K] split hi/lo bf16
struct PackDesc { const float* src; u16* dh; u16* dl; int K, N, sk, sh; };
struct PackArgs { PackDesc d[20]; int n; };
__global__ void k_pack2(PackArgs a) {
  PackDesc de = a.d[blockIdx.y];
  int total = de.K * de.N;
  for (int i = blockIdx.x*256 + threadIdx.x; i < total; i += gridDim.x*256) {
    int k = i / de.N, n = i - k*de.N;
    float x = de.src[(size_t)k*de.sk + (n & 127) + (n >> 7)*de.sh];
    u16 h = f2bf(x);
    de.dh[(size_t)n*de.K + k] = h;
    de.dl[(size_t)n*de.K + k] = f2bf(x - bf2f(h));
  }
}

__global__ void k_init_nodes(const int* __restrict__ seq, const float* __restrict__ emb,
                             float* __restrict__ nodes_f) {
  int i = blockIdx.x*256 + threadIdx.x;
  if (i >= NN*DD) return;
  int n = i >> 7, d = i & 127;
  nodes_f[i] = emb[seq[n]*DD + d];
}

__global__ void k_rbf_s(const float* __restrict__ dist, const float* __restrict__ W,
                        const float* __restrict__ b, float* __restrict__ eattr_f) {
  int e = blockIdx.x, t = threadIdx.x;   // 128 threads/edge
  float d = dist[e];
  float acc = b[t];
#pragma unroll
  for (int k = 0; k < 16; ++k) {
    float mu = 2.f + (20.f/15.f)*(float)k;
    float z = (d - mu)*0.8f;
    float r = expf(-z*z) + 1e-8f;
    acc += r*W[k*DD + t];
  }
  eattr_f[(size_t)e*DD + t] = acc;
}

__global__ void k_hist(const int* __restrict__ snk, int* __restrict__ deg) {
  int e = blockIdx.x*256 + threadIdx.x;
  if (e < EE) atomicAdd(&deg[snk[e]], 1);
}
__global__ void k_scan(const int* __restrict__ deg, int* __restrict__ ptr, int* __restrict__ cursor, int n) {
  __shared__ int buf[1024];
  __shared__ int carry_s;
  int tid = threadIdx.x;
  if (tid == 0) carry_s = 0;
  __syncthreads();
  for (int base = 0; base < n; base += 1024) {
    int i = base + tid;
    int v = (i < n) ? deg[i] : 0;
    buf[tid] = v;
    __syncthreads();
    for (int off = 1; off < 1024; off <<= 1) {
      int t = (tid >= off) ? buf[tid - off] : 0;
      __syncthreads();
      buf[tid] += t;
      __syncthreads();
    }
    int excl = buf[tid] - v;
    int carry = carry_s;
    if (i < n) { ptr[i] = carry + excl; cursor[i] = carry + excl; }
    __syncthreads();
    if (tid == 1023) carry_s = carry + buf[1023];
    __syncthreads();
  }
  if (tid == 0) ptr[n] = carry_s;
}
__global__ void k_scatter(const int* __restrict__ snk, int* __restrict__ cursor, int* __restrict__ csr) {
  int e = blockIdx.x*256 + threadIdx.x;
  if (e < EE) { int p = atomicAdd(&cursor[snk[e]], 1); csr[p] = e; }
}

__global__ void k_score_reduce(const float* __restrict__ Zs, const float* __restrict__ aA,
                               const float* __restrict__ aAb, float* __restrict__ scores, int rows) {
  int r = blockIdx.x*4 + (threadIdx.x >> 6);
  if (r >= rows) return;
  int lane = threadIdx.x & 63;
  const float* z = Zs + (size_t)r*HDIM + lane*8;
  float p = 0.f;
#pragma unroll
  for (int j = 0; j < 8; ++j) p += z[j] * aA[lane*8 + j];
  p += __shfl_xor(p, 1, 64); p += __shfl_xor(p, 2, 64);
  p += __shfl_xor(p, 4, 64); p += __shfl_xor(p, 8, 64);
  if ((lane & 15) == 0) scores[(size_t)r*4 + (lane >> 4)] = p + aAb[lane >> 4];
}

__global__ void k_softmax(const float* __restrict__ scores, const int* __restrict__ ptr,
                          const int* __restrict__ csr, float* __restrict__ att, int nnodes) {
  int node = blockIdx.x*4 + (threadIdx.x >> 6);
  if (node >= nnodes) return;
  int lane = threadIdx.x & 63;
  int h = lane >> 4, j = lane & 15;
  int b = ptr[node], e = ptr[node+1];
  float mx = -1e30f;
  for (int i = b + j; i < e; i += 16) mx = fmaxf(mx, scores[(size_t)csr[i]*4 + h]);
  mx = fmaxf(mx, __shfl_xor(mx, 1, 64)); mx = fmaxf(mx, __shfl_xor(mx, 2, 64));
  mx = fmaxf(mx, __shfl_xor(mx, 4, 64)); mx = fmaxf(mx, __shfl_xor(mx, 8, 64));
  float s = 0.f;
  for (int i = b + j; i < e; i += 16) s += expf(scores[(size_t)csr[i]*4 + h] - mx);
  s += __shfl_xor(s, 1, 64); s += __shfl_xor(s, 2, 64);
  s += __shfl_xor(s, 4, 64); s += __shfl_xor(s, 8, 64);
  float norm = s + (float)(e - b)*1e-12f;
  float inv = (e > b) ? 1.f/norm : 0.f;
  for (int i = b + j; i < e; i += 16) {
    int ed = csr[i];
    att[(size_t)ed*4 + h] = expf(scores[(size_t)ed*4 + h] - mx)*inv;
  }
}

__global__ void k_aggregate(const float* __restrict__ att, const float* __restrict__ nupd,
                            const int* __restrict__ ptr, const int* __restrict__ csr,
                            float* __restrict__ agg) {
  int node = blockIdx.x; int d = threadIdx.x;  // 128 threads
  int b = ptr[node], e = ptr[node+1];
  float a0=0.f, a1=0.f, a2=0.f, a3=0.f;
  for (int i = b; i < e; ++i) {
    int ed = csr[i];
    float4 a = *(const float4*)(att + (size_t)ed*4);
    float v = nupd[(size_t)ed*DD + d];
    a0 += a.x*v; a1 += a.y*v; a2 += a.z*v; a3 += a.w*v;
  }
  size_t o = (size_t)node*HDIM + d;
  agg[o] = a0; agg[o+128] = a1; agg[o+256] = a2; agg[o+384] = a3;
}

// mode 0: x = nodes_f + upd ; mode 1: x = dense_f + upd. Writes nodes_f.
__global__ void k_ln_node(float* __restrict__ nodes_f,
                          const float* __restrict__ upd, const float* __restrict__ dense_f,
                          const float* __restrict__ g, const float* __restrict__ b,
                          int mode, int rows) {
  int r = blockIdx.x*4 + (threadIdx.x >> 6);
  if (r >= rows) return;
  int lane = threadIdx.x & 63;
  size_t o = (size_t)r*DD;
  float x0, x1;
  if (mode == 0) { x0 = nodes_f[o+lane]; x1 = nodes_f[o+lane+64]; }
  else           { x0 = dense_f[o+lane]; x1 = dense_f[o+lane+64]; }
  x0 += upd[o+lane]; x1 += upd[o+lane+64];
  float s = x0 + x1;
#pragma unroll
  for (int m = 1; m < 64; m <<= 1) s += __shfl_xor(s, m, 64);
  float mean = s * (1.f/128.f);
  float d0 = x0 - mean, d1 = x1 - mean;
  float vv = d0*d0 + d1*d1;
#pragma unroll
  for (int m = 1; m < 64; m <<= 1) vv += __shfl_xor(vv, m, 64);
  float inv = rsqrtf(vv*(1.f/128.f) + 1e-5f);
  nodes_f[o+lane]    = d0*inv*g[lane]    + b[lane];
  nodes_f[o+lane+64] = d1*inv*g[lane+64] + b[lane+64];
}

__global__ void k_ln_edge(float* __restrict__ eattr_f, const float* __restrict__ eu,
                          const float* __restrict__ g, const float* __restrict__ b, int rows) {
  int r = blockIdx.x*4 + (threadIdx.x >> 6);
  if (r >= rows) return;
  int lane = threadIdx.x & 63;
  size_t o = (size_t)r*DD;
  float x0 = eattr_f[o+lane]    + eu[o+lane];
  float x1 = eattr_f[o+lane+64] + eu[o+lane+64];
  float s = x0 + x1;
#pragma unroll
  for (int m = 1; m < 64; m <<= 1) s += __shfl_xor(s, m, 64);
  float mean = s * (1.f/128.f);
  float d0 = x0 - mean, d1 = x1 - mean;
  float vv = d0*d0 + d1*d1;
#pragma unroll
  for (int m = 1; m < 64; m <<= 1) vv += __shfl_xor(vv, m, 64);
  float inv = rsqrtf(vv*(1.f/128.f) + 1e-5f);
  eattr_f[o+lane]    = d0*inv*g[lane]    + b[lane];
  eattr_f[o+lane+64] = d1*inv*g[lane+64] + b[lane+64];
}

__global__ void k_finalize(const float* __restrict__ nodes_f, const float* __restrict__ eattr_f,
                           void* __restrict__ out, const int* __restrict__ flag) {
  int i = blockIdx.x*256 + threadIdx.x;
  if (i >= OUT_TOTAL) return;
  int fp = *flag;
  float v = (i < OUT_NODES) ? nodes_f[i] : eattr_f[i - OUT_NODES];
  if (fp) ((float*)out)[i] = v; else ((u16*)out)[i] = f2bf(v);
}

extern "C" void kernel_launch(void* const* d_in, const int* in_sizes, int n_in,
                              void* d_out, int out_size, void* d_ws, size_t ws_size,
                              hipStream_t stream)
{
  const int* seq_idx = (const int*)d_in[0];
  const int* esrc = (const int*)d_in[1];
  const int* esnk = ((const int*)d_in[1]) + EE;

  char* wsp = (char*)d_ws;
  size_t off = 0;
  auto carve = [&](size_t bytes)->char* {
    char* p = wsp + off; off += (bytes + 255) & ~(size_t)255; return p;
  };
  // Total ~232 MB (R2's 245.7 worked; R3's 308.6 faulted)
  int* flag       = (int*)carve(256);
  float* nodes_f  = (float*)carve((size_t)NN*DD*4);
  float* upd_f    = (float*)carve((size_t)NN*DD*4);
  float* eattr_f  = (float*)carve((size_t)EE*DD*4);
  float* B_a      = (float*)carve((size_t)EE*DD*4);
  float* B_b      = (float*)carve((size_t)EE*DD*4);
  float* scores   = (float*)carve((size_t)EE*4*4);
  float* att      = (float*)carve((size_t)EE*4*4);
  float* agg_f    = (float*)carve((size_t)NN*HDIM*4);
  float* dh_f     = (float*)carve((size_t)NN*HDIM*4);
  float* dense_f  = (float*)carve((size_t)NN*DD*4);
  u16* wpk_h      = (u16*)carve(557056ULL*2*2);
  u16* wpk_l      = (u16*)carve(557056ULL*2*2);
  int* deg        = (int*)carve((size_t)NN*4);
  int* ptrb       = (int*)carve((size_t)(NN+1)*4);
  int* cursor     = (int*)carve((size_t)NN*4);
  int* csr        = (int*)carve((size_t)EE*4);

  static const int FCNT[32] = {0,0,120000,2688,2048,128,393216,1024,1024,8,
    98304,256,32768,256,32768,256, 131072,1024,131072,256,
    98304,256,32768,256,32768,256, 131072,256, 256,256,256,256};
  float* cf[32];
  for (int i = 2; i < 32; ++i) cf[i] = (float*)carve((size_t)FCNT[i]*4);
  (void)ws_size; (void)in_sizes; (void)n_in; (void)out_size;

  // ---- detect float storage dtype, canonicalize to FP32 arena ----
  k_detect<<<1, 1024, 0, stream>>>((const u16*)d_in[2], 120000, flag);
  ConvArgs ca;
  for (int i = 2; i < 32; ++i) { ca.d[i-2].src = d_in[i]; ca.d[i-2].dst = cf[i]; ca.d[i-2].n = FCNT[i]; }
  hipLaunchKernelGGL(k_conv32, dim3(96, 30), dim3(256), 0, stream, ca, flag);

  // ---- pack weights to [N,K] split hi/lo bf16 ----
  const size_t PW_L = 557056;
  PackArgs pa; int nd = 0;
  for (int l = 0; l < 2; ++l) {
    size_t base = l*PW_L;
    auto add = [&](const float* s, size_t doff, int K, int N, int sk, int sh){
      pa.d[nd].src = s; pa.d[nd].dh = wpk_h + doff; pa.d[nd].dl = wpk_l + doff;
      pa.d[nd].K = K; pa.d[nd].N = N; pa.d[nd].sk = sk; pa.d[nd].sh = sh; ++nd; };
    add(cf[6]  + l*196608, base + 0,      384, 512, 128, 49152);  // aW^T (n = h*128+d)
    add(cf[10] + l*49152,  base + 196608, 384, 128, 128, 0);      // nmlp_W1
    add(cf[12] + l*16384,  base + 245760, 128, 128, 128, 0);      // nmlp_W2
    add(cf[14] + l*16384,  base + 262144, 128, 128, 128, 0);      // nmlp_W3
    add(cf[26] + l*65536,  base + 278528, 512, 128, 128, 0);      // aggr_W
    add(cf[16] + l*65536,  base + 344064, 128, 512, 512, 128);    // dmlp_W1
    add(cf[18] + l*65536,  base + 409600, 512, 128, 128, 0);      // dmlp_W2
    add(cf[20] + l*49152,  base + 475136, 384, 128, 128, 0);      // emlp_W1
    add(cf[22] + l*16384,  base + 524288, 128, 128, 128, 0);      // emlp_W2
    add(cf[24] + l*16384,  base + 540672, 128, 128, 128, 0);      // emlp_W3
  }
  pa.n = nd;
  hipLaunchKernelGGL(k_pack2, dim3(768, nd), dim3(256), 0, stream, pa);

  k_init_nodes<<<(NN*DD + 255)/256, 256, 0, stream>>>(seq_idx, cf[3], nodes_f);
  k_rbf_s<<<EE, 128, 0, stream>>>(cf[2], cf[4], cf[5], eattr_f);

  hipMemsetAsync(deg, 0, (size_t)NN*4, stream);
  k_hist<<<(EE + 255)/256, 256, 0, stream>>>(esnk, deg);
  k_scan<<<1, 1024, 0, stream>>>(deg, ptrb, cursor, NN);
  k_scatter<<<(EE + 255)/256, 256, 0, stream>>>(esnk, cursor, csr);

  for (int l = 0; l < 2; ++l) {
    const u16* bh = wpk_h + l*PW_L; const u16* bl = wpk_l + l*PW_L;
    // attention scores: gathered chunks [15000,384]@[384,512] -> lrelu fp32 -> dot aA
    for (int ch = 0; ch < 8; ++ch) {
      k_gemm_gsp3<<<dim3(118, 4), 256, 0, stream>>>(nodes_f, eattr_f, esrc, esnk, ch*15000,
                                                    bh + 0, bl + 0, cf[7] + l*512, B_a, 15000, 512, 2);
      k_score_reduce<<<3750, 256, 0, stream>>>(B_a, cf[8] + l*512, cf[9] + l*4,
                                               scores + (size_t)ch*15000*4, 15000);
    }
    // node-update MLP on edges (nupd -> B_b)
    k_gemm_gsp3<<<dim3(938,1), 256, 0, stream>>>(nodes_f, eattr_f, esrc, esnk, 0,
                                                 bh + 196608, bl + 196608, cf[11] + l*128, B_b, EE, 128, 4);
    k_gemm_sp3<<<dim3(938,1), 256, 0, stream>>>(B_b, bh + 245760, bl + 245760, cf[13] + l*128, B_a, EE, 128, 128, 4);
    k_gemm_sp3<<<dim3(938,1), 256, 0, stream>>>(B_a, bh + 262144, bl + 262144, cf[15] + l*128, B_b, EE, 128, 128, 3);
    // scatter softmax + aggregation
    k_softmax<<<(NN + 3)/4, 256, 0, stream>>>(scores, ptrb, csr, att, NN);
    k_aggregate<<<NN, 128, 0, stream>>>(att, B_b, ptrb, csr, agg_f);
    // upd = agg @ aggr_W + b
    k_gemm_sp3<<<dim3(47,1), 256, 0, stream>>>(agg_f, bh + 278528, bl + 278528, cf[27] + l*128, upd_f, NN, 512, 128, 3);
    k_ln_node<<<(NN + 3)/4, 256, 0, stream>>>(nodes_f, upd_f, (const float*)nullptr,
                                              cf[28] + l*128, cf[29] + l*128, 0, NN);
    // dense MLP
    k_gemm_sp3<<<dim3(47,4), 256, 0, stream>>>(nodes_f, bh + 344064, bl + 344064, cf[17] + l*512, dh_f, NN, 128, 512, 4);
    k_gemm_sp3<<<dim3(47,1), 256, 0, stream>>>(dh_f, bh + 409600, bl + 409600, cf[19] + l*128, dense_f, NN, 512, 128, 3);
    k_ln_node<<<(NN + 3)/4, 256, 0, stream>>>(nodes_f, upd_f, dense_f,
                                              cf[28] + l*128, cf[29] + l*128, 1, NN);
    // edge MLP (eu -> B_a)
    k_gemm_gsp3<<<dim3(938,1), 256, 0, stream>>>(nodes_f, eattr_f, esrc, esnk, 0,
                                                 bh + 475136, bl + 475136, cf[21] + l*128, B_a, EE, 128, 4);
    k_gemm_sp3<<<dim3(938,1), 256, 0, stream>>>(B_a, bh + 524288, bl + 524288, cf[23] + l*128, B_b, EE, 128, 128, 4);
    k_gemm_sp3<<<dim3(938,1), 256, 0, stream>>>(B_b, bh + 540672, bl + 540672, cf[25] + l*128, B_a, EE, 128, 128, 3);
    k_ln_edge<<<(EE + 3)/4, 256, 0, stream>>>(eattr_f, B_a, cf[30] + l*128, cf[31] + l*128, EE);
  }
  k_finalize<<<(OUT_TOTAL + 255)/256, 256, 0, stream>>>(nodes_f, eattr_f, d_out, flag);
}